// Round 1
// baseline (218.813 us; speedup 1.0000x reference)
//
#include <hip/hip_runtime.h>

#define N_VERTS 53215
#define EXP_DIM 29
#define SHP_DIM 199
#define HEIGHT_F 450.0f
#define ASPECT_XY (224.0f / 450.0f)

// One vertex per block (192 threads = 3 waves). Wave w handles row 3*vert+w:
// coalesced per-lane loads of the 199-float w_shp row + 29-float w_exp row,
// butterfly shuffle-reduce over 64 lanes, then thread 0 applies the pose
// transform. Memory-bound: ~146 MB of W reads dominates everything.
__global__ __launch_bounds__(192) void pca_transform_kernel(
    const float* __restrict__ pose,       // 12
    const float* __restrict__ alpha_exp,  // 29
    const float* __restrict__ alpha_shp,  // 199
    const float* __restrict__ u_base,     // 3*N_VERTS
    const float* __restrict__ w_exp,      // 3*N_VERTS x 29
    const float* __restrict__ w_shp,      // 3*N_VERTS x 199
    float* __restrict__ out)              // N_VERTS x 3
{
    const int vert = blockIdx.x;
    const int wave = threadIdx.x >> 6;   // 0..2  (x,y,z row of this vertex)
    const int lane = threadIdx.x & 63;
    const int row  = vert * 3 + wave;

    // --- dot(w_shp[row,:], alpha_shp) + dot(w_exp[row,:], alpha_exp) ---
    const float* __restrict__ srow = w_shp + (size_t)row * SHP_DIM;
    float sum = 0.0f;
    // 199 = 3*64 + 7 -> lanes 0..6 do 4 iters, rest do 3.
    #pragma unroll 4
    for (int k = lane; k < SHP_DIM; k += 64)
        sum += srow[k] * alpha_shp[k];

    const float* __restrict__ erow = w_exp + (size_t)row * EXP_DIM;
    if (lane < EXP_DIM)
        sum += erow[lane] * alpha_exp[lane];

    // --- 64-lane butterfly reduction ---
    #pragma unroll
    for (int off = 32; off > 0; off >>= 1)
        sum += __shfl_xor(sum, off, 64);

    __shared__ float v[3];
    if (lane == 0)
        v[wave] = u_base[row] + sum;
    __syncthreads();

    if (threadIdx.x == 0) {
        const float vx = v[0], vy = v[1], vz = v[2];
        const float tx = pose[3], ty = pose[7];
        const float s  = pose[3] + pose[7] + pose[11];
        const float ox = s * (pose[0] * vx + pose[1] * vy + pose[2]  * vz) + tx;
        const float oy = -(s * (pose[4] * vx + pose[5] * vy + pose[6] * vz) + ty) + HEIGHT_F;
        const float oz = s * (pose[8] * vx + pose[9] * vy + pose[10] * vz);
        float* o = out + (size_t)vert * 3;
        o[0] = ox * ASPECT_XY;
        o[1] = oy * ASPECT_XY;
        o[2] = oz;  // aspect z = 1.0
    }
}

extern "C" void kernel_launch(void* const* d_in, const int* in_sizes, int n_in,
                              void* d_out, int out_size, void* d_ws, size_t ws_size,
                              hipStream_t stream) {
    const float* pose      = (const float*)d_in[0];
    const float* alpha_exp = (const float*)d_in[1];
    const float* alpha_shp = (const float*)d_in[2];
    const float* u_base    = (const float*)d_in[3];
    const float* w_exp     = (const float*)d_in[4];
    const float* w_shp     = (const float*)d_in[5];
    float* out = (float*)d_out;

    pca_transform_kernel<<<N_VERTS, 192, 0, stream>>>(
        pose, alpha_exp, alpha_shp, u_base, w_exp, w_shp, out);
}

// Round 2
// 207.316 us; speedup vs baseline: 1.0555x; 1.0555x over previous
//
#include <hip/hip_runtime.h>

#define N_VERTS 53215
#define EXP_DIM 29
#define SHP_DIM 199
#define HEIGHT_F 450.0f
#define ASPECT_XY (224.0f / 450.0f)

// Grid-stride, wave-per-vertex, no barriers. Each 64-lane wave processes one
// vertex per iteration: 3 contiguous 199-float rows of w_shp (lane-strided,
// coalesced) + 3 rows of w_exp. Alpha vectors are loop-invariant per lane ->
// hoisted into 5 registers before the loop. 15 independent loads in flight
// per iteration per wave; 2048 blocks x 4 waves = 32 waves/CU keeps ~100 KB
// outstanding per CU (need ~9 KB for 6.3 TB/s at ~900cy latency).
__global__ __launch_bounds__(256, 8) void pca_transform_kernel(
    const float* __restrict__ pose,       // 12
    const float* __restrict__ alpha_exp,  // 29
    const float* __restrict__ alpha_shp,  // 199
    const float* __restrict__ u_base,     // 3*N_VERTS
    const float* __restrict__ w_exp,      // 3*N_VERTS x 29
    const float* __restrict__ w_shp,      // 3*N_VERTS x 199
    float* __restrict__ out)              // N_VERTS x 3
{
    const int lane   = threadIdx.x & 63;
    const int gwave  = (int)((blockIdx.x * blockDim.x + threadIdx.x) >> 6);
    const int nwaves = (int)((gridDim.x * blockDim.x) >> 6);

    // Pose is wave-uniform and loop-invariant -> SGPRs.
    const float p0 = pose[0], p1 = pose[1], p2  = pose[2],  p3  = pose[3];
    const float p4 = pose[4], p5 = pose[5], p6  = pose[6],  p7  = pose[7];
    const float p8 = pose[8], p9 = pose[9], p10 = pose[10], p11 = pose[11];
    const float s  = p3 + p7 + p11;

    // Per-lane alpha slice is loop-invariant: hoist to registers.
    // 199 = 3*64 + 7 ; clamp tail address, zero the weight (no exec-mask br).
    const int  k3 = (lane < 7)  ? lane + 192 : 198;
    const int  ke = (lane < EXP_DIM) ? lane : (EXP_DIM - 1);
    const float a0 = alpha_shp[lane];
    const float a1 = alpha_shp[lane + 64];
    const float a2 = alpha_shp[lane + 128];
    const float a3 = (lane < 7) ? alpha_shp[k3] : 0.0f;
    const float ae = (lane < EXP_DIM) ? alpha_exp[ke] : 0.0f;

    for (int v = gwave; v < N_VERTS; v += nwaves) {
        const float* __restrict__ sx_p = w_shp + (size_t)(3 * v) * SHP_DIM;
        const float* __restrict__ sy_p = sx_p + SHP_DIM;
        const float* __restrict__ sz_p = sy_p + SHP_DIM;
        const float* __restrict__ ex_p = w_exp + (size_t)(3 * v) * EXP_DIM;

        // Issue all 15 row loads back-to-back (max MLP), then reduce.
        const float x0 = sx_p[lane], x1 = sx_p[lane + 64], x2 = sx_p[lane + 128], x3 = sx_p[k3];
        const float y0 = sy_p[lane], y1 = sy_p[lane + 64], y2 = sy_p[lane + 128], y3 = sy_p[k3];
        const float z0 = sz_p[lane], z1 = sz_p[lane + 64], z2 = sz_p[lane + 128], z3 = sz_p[k3];
        const float xe = ex_p[ke], ye = ex_p[EXP_DIM + ke], ze = ex_p[2 * EXP_DIM + ke];

        float sx = x0 * a0 + x1 * a1 + x2 * a2 + x3 * a3 + xe * ae;
        float sy = y0 * a0 + y1 * a1 + y2 * a2 + y3 * a3 + ye * ae;
        float sz = z0 * a0 + z1 * a1 + z2 * a2 + z3 * a3 + ze * ae;

        // Three interleaved 64-lane butterflies (independent dep chains).
        #pragma unroll
        for (int off = 32; off > 0; off >>= 1) {
            sx += __shfl_xor(sx, off, 64);
            sy += __shfl_xor(sy, off, 64);
            sz += __shfl_xor(sz, off, 64);
        }

        const float vx = sx + u_base[3 * v + 0];
        const float vy = sy + u_base[3 * v + 1];
        const float vz = sz + u_base[3 * v + 2];

        const float ox = ASPECT_XY * (s * (p0 * vx + p1 * vy + p2  * vz) + p3);
        const float oy = ASPECT_XY * (HEIGHT_F - (s * (p4 * vx + p5 * vy + p6 * vz) + p7));
        const float oz = s * (p8 * vx + p9 * vy + p10 * vz);

        if (lane == 0) {
            float* o = out + (size_t)v * 3;
            o[0] = ox; o[1] = oy; o[2] = oz;
        }
    }
}

extern "C" void kernel_launch(void* const* d_in, const int* in_sizes, int n_in,
                              void* d_out, int out_size, void* d_ws, size_t ws_size,
                              hipStream_t stream) {
    const float* pose      = (const float*)d_in[0];
    const float* alpha_exp = (const float*)d_in[1];
    const float* alpha_shp = (const float*)d_in[2];
    const float* u_base    = (const float*)d_in[3];
    const float* w_exp     = (const float*)d_in[4];
    const float* w_shp     = (const float*)d_in[5];
    float* out = (float*)d_out;

    // 2048 blocks x 256 thr = 8192 waves (32 waves/CU), ~6.5 vertices/wave.
    pca_transform_kernel<<<2048, 256, 0, stream>>>(
        pose, alpha_exp, alpha_shp, u_base, w_exp, w_shp, out);
}